// Round 2
// baseline (242.577 us; speedup 1.0000x reference)
//
#include <hip/hip_runtime.h>

#define BATCH 8
#define NPTS  12000
#define FDIM  128
#define SDIM  16
#define ODIM  128
#define KDIM  (SDIM * FDIM)      // 2048
#define MTOT  (BATCH * NPTS)     // 96000

#define BM 128
#define BK 64
#define LDA 72                   // BK + 8 pad (bf16 elements) -> row stride 144 B

typedef __bf16 bf16x8 __attribute__((ext_vector_type(8)));
typedef float  f32x4  __attribute__((ext_vector_type(4)));
typedef float  f32x8  __attribute__((ext_vector_type(8)));

__global__ __launch_bounds__(256, 2)
void spiral_gemm_kernel(const float* __restrict__ x,     // (B, N, F) fp32
                        const float* __restrict__ W,     // (OUT, K) fp32
                        const float* __restrict__ bias,  // (OUT,) fp32
                        const int*   __restrict__ idx,   // (N, S) int32
                        const float* __restrict__ zp,    // (N,) fp32
                        float*       __restrict__ out)   // (B, N, OUT) fp32
{
    __shared__ __bf16 As[BM * LDA];
    __shared__ __bf16 Ws[ODIM * LDA];

    const int tid  = threadIdx.x;
    const int wave = tid >> 6;
    const int lane = tid & 63;
    const int m0   = blockIdx.x * BM;

    // staging roles: 8 threads per row (8 elements each), 32 rows per pass, 4 passes
    const int srow   = tid >> 3;   // 0..31
    const int schunk = tid & 7;    // 0..7

    // Per-thread row info for the gathered A tile (rows fixed across K loop)
    int          a_n[4];
    const float* a_xb[4];
#pragma unroll
    for (int p = 0; p < 4; ++p) {
        int m   = m0 + srow + p * 32;
        int bb  = m / NPTS;
        a_n[p]  = m - bb * NPTS;
        a_xb[p] = x + (size_t)bb * (NPTS * FDIM);
    }

    f32x4 acc[4][4];
#pragma unroll
    for (int i = 0; i < 4; ++i)
#pragma unroll
        for (int j = 0; j < 4; ++j)
            acc[i][j] = f32x4{0.f, 0.f, 0.f, 0.f};

    const int wm   = (wave >> 1) * 64;   // 2x2 waves, each 64x64
    const int wn   = (wave & 1) * 64;
    const int lrow = lane & 15;
    const int quad = lane >> 4;

    for (int kt = 0; kt < KDIM / BK; ++kt) {   // 32 iterations
        const int s  = kt >> 1;                // spiral neighbor index
        const int f0 = (kt & 1) * BK;          // 0 or 64 within the gathered row
        __syncthreads();
        // --- stage gathered A tile: 128 rows x 64 elements, fp32 -> bf16 ---
#pragma unroll
        for (int p = 0; p < 4; ++p) {
            const int r = srow + p * 32;
            const int g = idx[a_n[p] * SDIM + s];
            const f32x8 v = *reinterpret_cast<const f32x8*>(
                a_xb[p] + (size_t)g * FDIM + f0 + schunk * 8);
            bf16x8 h;
#pragma unroll
            for (int e = 0; e < 8; ++e) h[e] = (__bf16)v[e];
            *reinterpret_cast<bf16x8*>(&As[r * LDA + schunk * 8]) = h;
        }
        // --- stage W tile: 128 o-rows x 64 elements, fp32 -> bf16 ---
        const int kbase = kt * BK;
#pragma unroll
        for (int p = 0; p < 4; ++p) {
            const int r = srow + p * 32;
            const f32x8 v = *reinterpret_cast<const f32x8*>(
                W + (size_t)r * KDIM + kbase + schunk * 8);
            bf16x8 h;
#pragma unroll
            for (int e = 0; e < 8; ++e) h[e] = (__bf16)v[e];
            *reinterpret_cast<bf16x8*>(&Ws[r * LDA + schunk * 8]) = h;
        }
        __syncthreads();
        // --- compute: 2 k-steps of 32, 16 MFMAs each ---
#pragma unroll
        for (int kk = 0; kk < 2; ++kk) {
            const int koff = kk * 32 + quad * 8;
            bf16x8 a[4], b[4];
#pragma unroll
            for (int i = 0; i < 4; ++i)
                a[i] = *reinterpret_cast<const bf16x8*>(
                    &As[(wm + i * 16 + lrow) * LDA + koff]);
#pragma unroll
            for (int j = 0; j < 4; ++j)
                b[j] = *reinterpret_cast<const bf16x8*>(
                    &Ws[(wn + j * 16 + lrow) * LDA + koff]);
#pragma unroll
            for (int i = 0; i < 4; ++i)
#pragma unroll
                for (int j = 0; j < 4; ++j)
                    acc[i][j] = __builtin_amdgcn_mfma_f32_16x16x32_bf16(
                        a[i], b[j], acc[i][j], 0, 0, 0);
        }
    }

    // --- epilogue: bias + relu + zero_padding, C/D layout col=lane&15, row=quad*4+reg ---
#pragma unroll
    for (int i = 0; i < 4; ++i) {
#pragma unroll
        for (int r = 0; r < 4; ++r) {
            const int row = wm + i * 16 + quad * 4 + r;
            const int m   = m0 + row;
            const int bb  = m / NPTS;
            const int nn  = m - bb * NPTS;
            const float z = zp[nn];
            float* orow   = out + (size_t)m * ODIM;
#pragma unroll
            for (int j = 0; j < 4; ++j) {
                const int col = wn + j * 16 + lrow;
                float v = acc[i][j][r] + bias[col];
                v = fmaxf(v, 0.f);
                v *= z;
                orow[col] = v;
            }
        }
    }
}

extern "C" void kernel_launch(void* const* d_in, const int* in_sizes, int n_in,
                              void* d_out, int out_size, void* d_ws, size_t ws_size,
                              hipStream_t stream) {
    const float* x    = (const float*)d_in[0];
    const float* W    = (const float*)d_in[1];
    const float* bias = (const float*)d_in[2];
    const int*   idx  = (const int*)d_in[3];
    const float* zp   = (const float*)d_in[4];
    float*       out  = (float*)d_out;

    spiral_gemm_kernel<<<dim3(MTOT / BM), dim3(256), 0, stream>>>(
        x, W, bias, idx, zp, out);
}